// Round 12
// baseline (110.402 us; speedup 1.0000x reference)
//
#include <hip/hip_runtime.h>

typedef float v2f __attribute__((ext_vector_type(2)));

#define P_TOTAL 8192
#define F_TOTAL 2048
#define TPB     256                      // 4 waves; wave w owns points 2w, 2w+1
#define CHUNK   256                      // tris staged per LDS pass
#define NCHUNK  (F_TOTAL / CHUNK)        // 8

// Correctly-rounded f32 division via shared refined reciprocal (Markstein).
// Valid here: D = fmax(.,1e-12) is normal, num finite. Tie partners present
// identical (num,D) bits -> identical q bits -> np's exact-tie structure kept.
// (R8-verified bit-exact on HW.)
__device__ __forceinline__ float refine_rcp(float D) {
#pragma clang fp contract(off)
    float r0 = __builtin_amdgcn_rcpf(D);
    float e1 = __builtin_fmaf(-D, r0, 1.0f);
    return __builtin_fmaf(e1, r0, r0);
}
__device__ __forceinline__ float div_rn(float num, float D, float r) {
#pragma clang fp contract(off)
    float q0 = num * r;
    float e  = __builtin_fmaf(-D, q0, num);
    return __builtin_fmaf(e, r, q0);
}

// Scalar region-select, bit-exact vs numpy (proven R2..R9): first-match
// region, then two divisions with reference-identical operands sharing one
// reciprocal of the common denominator D.
__device__ __forceinline__ void region_select(
    float d1, float d2, float d3, float d4, float d5, float d6,
    float va, float vb, float vc, float d43, float d56,
    float g1, float g2, float g3, float g4,
    float& bu, float& bv, float& bw)
{
#pragma clang fp contract(off)
    float G1 = fmaxf(g1, 1e-12f);          // t_ab denom
    float G2 = fmaxf(g2, 1e-12f);          // t_ac denom
    float G3 = fmaxf(g3, 1e-12f);          // t_bc denom
    float G4 = fmaxf(g4, 1e-12f);          // interior denom

    bool cA  = (d1 <= 0.f) & (d2 <= 0.f);
    bool cB  = (d3 >= 0.f) & (d4 <= d3);
    bool cAB = (vc <= 0.f) & (d1 >= 0.f) & (d3 <= 0.f);
    bool cC  = (d6 >= 0.f) & (d5 <= d6);
    bool cAC = (vb <= 0.f) & (d2 >= 0.f) & (d6 <= 0.f);
    bool cBC = (va <= 0.f) & (d43 >= 0.f) & (d56 >= 0.f);

    float nv = cA ? 0.f : cB ? 1.f : cAB ? d1 : cC ? 0.f
             : cAC ? 0.f : cBC ? d43 : vb;
    float nw = cA ? 0.f : cB ? 0.f : cAB ? 0.f : cC ? 1.f
             : cAC ? d2 : cBC ? d43 : vc;
    float D  = cA ? 1.f : cB ? 1.f : cAB ? G1 : cC ? 1.f
             : cAC ? G2 : cBC ? G3 : G4;
    bool fBC = cBC && !(cA || cB || cAB || cC || cAC);

    float r   = refine_rcp(D);
    float qv  = div_rn(nv, D, r);          // == RN(nv/D), ref-identical operands
    float bww = div_rn(nw, D, r);
    float bvv = fBC ? (1.0f - qv) : qv;    // reference: 1.0 - t_bc
    bv = bvv; bw = bww;
    bu = (1.0f - bvv) - bww;
}

// One point vs a packed pair of triangles: R8's verbatim v2f pipeline.
// (No inline asm — R10/R11's hand VOP3P corrupted the high element twice;
// compiler-generated vector code is the proven-correct path.)
__device__ __forceinline__ v2f eval_pair(
    float px, float py, float pz,
    v2f ax, v2f ay, v2f az, v2f bx, v2f by, v2f bz, v2f cx, v2f cy, v2f cz,
    v2f abx, v2f aby, v2f abz, v2f acx, v2f acy, v2f acz)
{
#pragma clang fp contract(off)
    v2f apx = px - ax, apy = py - ay, apz = pz - az;
    v2f d1 = (abx * apx + aby * apy) + abz * apz;
    v2f d2 = (acx * apx + acy * apy) + acz * apz;
    v2f bpx = px - bx, bpy = py - by, bpz = pz - bz;
    v2f d3 = (abx * bpx + aby * bpy) + abz * bpz;
    v2f d4 = (acx * bpx + acy * bpy) + acz * bpz;
    v2f cpx = px - cx, cpy = py - cy, cpz = pz - cz;
    v2f d5 = (abx * cpx + aby * cpy) + abz * cpz;
    v2f d6 = (acx * cpx + acy * cpy) + acz * cpz;

    v2f vc = d1 * d4 - d3 * d2;
    v2f vb = d5 * d2 - d1 * d6;
    v2f va = d3 * d6 - d5 * d4;
    v2f d43 = d4 - d3, d56 = d5 - d6;
    v2f g1 = d1 - d3;                 // t_ab denom (pre-fmax)
    v2f g2 = d2 - d6;                 // t_ac denom
    v2f g3 = d43 + d56;               // t_bc denom
    v2f g4 = (va + vb) + vc;          // interior denom

    float bu0, bv0, bw0, bu1, bv1, bw1;
    region_select(d1.x, d2.x, d3.x, d4.x, d5.x, d6.x,
                  va.x, vb.x, vc.x, d43.x, d56.x,
                  g1.x, g2.x, g3.x, g4.x, bu0, bv0, bw0);
    region_select(d1.y, d2.y, d3.y, d4.y, d5.y, d6.y,
                  va.y, vb.y, vc.y, d43.y, d56.y,
                  g1.y, g2.y, g3.y, g4.y, bu1, bv1, bw1);
    v2f bu = {bu0, bu1}, bv = {bv0, bv1}, bw = {bw0, bw1};

    // reference: cp = a*bu + b*bv + c*bw; dist2 = sum((p-cp)^2)
    v2f cpx2 = (ax * bu + bx * bv) + cx * bw;
    v2f cpy2 = (ay * bu + by * bv) + cy * bw;
    v2f cpz2 = (az * bu + bz * bv) + cz * bw;
    v2f dx = px - cpx2, dy = py - cpy2, dz = pz - cpz2;
    return (dx * dx + dy * dy) + dz * dz;
}

// Wave-per-2-points exact scan, 2 tris/lane. Triangle LDS reads, edge
// vectors, staging, and loop overhead are shared across both points
// (R8's per-pair arithmetic verbatim -> bit-exact). Single-buffer staging
// (R9: dbuf neutral). No global atomics (R5 lesson).
__global__ __launch_bounds__(TPB) void msdf_main(
    const float* __restrict__ verts, const int* __restrict__ faces,
    const float* __restrict__ points, float* __restrict__ out)
{
#pragma clang fp contract(off)
    __shared__ float sT[9][CHUNK];       // 9 KB, component-major
    const int tid  = threadIdx.x;
    const int lane = tid & 63;
    const int w    = tid >> 6;
    const int pA   = blockIdx.x * 8 + 2 * w;      // wave-uniform point ids
    const int pB   = pA + 1;

    const float pxA = points[3 * pA], pyA = points[3 * pA + 1], pzA = points[3 * pA + 2];
    const float pxB = points[3 * pB], pyB = points[3 * pB + 1], pzB = points[3 * pB + 2];

    unsigned int bbA = 0xFFFFFFFFu; int biA = 0;
    unsigned int bbB = 0xFFFFFFFFu; int biB = 0;

    for (int c = 0; c < NCHUNK; ++c) {
        __syncthreads();                 // protect LDS buffer reuse
        {   // stage: thread tid gathers tri c*256+tid; conflict-free writes
            int tg = c * CHUNK + tid;
            int i0 = faces[3 * tg + 0], i1 = faces[3 * tg + 1], i2 = faces[3 * tg + 2];
            sT[0][tid] = verts[3 * i0]; sT[1][tid] = verts[3 * i0 + 1]; sT[2][tid] = verts[3 * i0 + 2];
            sT[3][tid] = verts[3 * i1]; sT[4][tid] = verts[3 * i1 + 1]; sT[5][tid] = verts[3 * i1 + 2];
            sT[6][tid] = verts[3 * i2]; sT[7][tid] = verts[3 * i2 + 1]; sT[8][tid] = verts[3 * i2 + 2];
        }
        __syncthreads();

        #pragma unroll
        for (int k = 0; k < 2; ++k) {
            int base = k * 128 + 2 * lane;           // even: 8B-aligned pair
            v2f ax = *(const v2f*)&sT[0][base];
            v2f ay = *(const v2f*)&sT[1][base];
            v2f az = *(const v2f*)&sT[2][base];
            v2f bx = *(const v2f*)&sT[3][base];
            v2f by = *(const v2f*)&sT[4][base];
            v2f bz = *(const v2f*)&sT[5][base];
            v2f cx = *(const v2f*)&sT[6][base];
            v2f cy = *(const v2f*)&sT[7][base];
            v2f cz = *(const v2f*)&sT[8][base];

            // shared edge vectors (same bits as computing per point)
            v2f abx = bx - ax, aby = by - ay, abz = bz - az;
            v2f acx = cx - ax, acy = cy - ay, acz = cz - az;

            v2f dA = eval_pair(pxA, pyA, pzA, ax, ay, az, bx, by, bz,
                               cx, cy, cz, abx, aby, abz, acx, acy, acz);
            v2f dB = eval_pair(pxB, pyB, pzB, ax, ay, az, bx, by, bz,
                               cx, cy, cz, abx, aby, abz, acx, acy, acz);

            int idx0 = c * CHUNK + base;
            unsigned int a0 = __float_as_uint(dA.x);      // even tri first
            if (a0 < bbA) { bbA = a0; biA = idx0; }
            unsigned int a1 = __float_as_uint(dA.y);
            if (a1 < bbA) { bbA = a1; biA = idx0 + 1; }
            unsigned int b0 = __float_as_uint(dB.x);
            if (b0 < bbB) { bbB = b0; biB = idx0; }
            unsigned int b1 = __float_as_uint(dB.y);
            if (b1 < bbB) { bbB = b1; biB = idx0 + 1; }
        }
    }

    // in-wave packed mins: smallest (bits, idx) == first-match argmin
    unsigned long long keyA =
        ((unsigned long long)bbA << 32) | (unsigned int)biA;
    unsigned long long keyB =
        ((unsigned long long)bbB << 32) | (unsigned int)biB;
    #pragma unroll
    for (int off = 32; off > 0; off >>= 1) {
        unsigned int hiA = (unsigned int)(keyA >> 32);
        unsigned int loA = (unsigned int)(keyA & 0xFFFFFFFFu);
        unsigned int ohiA = __shfl_down(hiA, off, 64);
        unsigned int oloA = __shfl_down(loA, off, 64);
        unsigned long long okA = ((unsigned long long)ohiA << 32) | oloA;
        keyA = (okA < keyA) ? okA : keyA;
        unsigned int hiB = (unsigned int)(keyB >> 32);
        unsigned int loB = (unsigned int)(keyB & 0xFFFFFFFFu);
        unsigned int ohiB = __shfl_down(hiB, off, 64);
        unsigned int oloB = __shfl_down(loB, off, 64);
        unsigned long long okB = ((unsigned long long)ohiB << 32) | oloB;
        keyB = (okB < keyB) ? okB : keyB;
    }
    if (lane == 0) {
        out[1 + pA]           = __uint_as_float((unsigned int)(keyA >> 32));
        out[1 + P_TOTAL + pA] = (float)(unsigned int)(keyA & 0xFFFFFFFFu);
        out[1 + pB]           = __uint_as_float((unsigned int)(keyB >> 32));
        out[1 + P_TOTAL + pB] = (float)(unsigned int)(keyB & 0xFFFFFFFFu);
    }
}

// Deterministic single-block loss reduction: out[0] = sum(dist) * 1000/P.
// No atomics (R5: 8192 same-address atomicAdds cost +66us serialized tail).
__global__ __launch_bounds__(256) void msdf_loss(float* __restrict__ out)
{
    __shared__ float wsum[4];
    float s = 0.f;
    for (int k = 0; k < P_TOTAL / 256; ++k)
        s += out[1 + k * 256 + threadIdx.x];
    #pragma unroll
    for (int off = 32; off > 0; off >>= 1) s += __shfl_down(s, off, 64);
    int lane = threadIdx.x & 63, w = threadIdx.x >> 6;
    if (lane == 0) wsum[w] = s;
    __syncthreads();
    if (threadIdx.x == 0) {
        float tot = ((wsum[0] + wsum[1]) + wsum[2]) + wsum[3];
        out[0] = tot * (1000.0f / (float)P_TOTAL);
    }
}

extern "C" void kernel_launch(void* const* d_in, const int* in_sizes, int n_in,
                              void* d_out, int out_size, void* d_ws, size_t ws_size,
                              hipStream_t stream) {
    const float* verts  = (const float*)d_in[0];
    const int*   faces  = (const int*)d_in[1];
    const float* points = (const float*)d_in[2];
    float* out = (float*)d_out;

    msdf_main<<<dim3(P_TOTAL / 8), dim3(TPB), 0, stream>>>(verts, faces, points, out);
    msdf_loss<<<dim3(1), dim3(256), 0, stream>>>(out);
}

// Round 13
// 96.696 us; speedup vs baseline: 1.1417x; 1.1417x over previous
//
#include <hip/hip_runtime.h>
#include <float.h>

#define P_TOTAL 8192
#define F_TOTAL 2048
#define TPB     256                      // 4 waves; wave w owns point base+w
#define CHUNK   256                      // tris staged per LDS pass
#define NCHUNK  (F_TOTAL / CHUNK)        // 8

// Correctly-rounded f32 division via shared refined reciprocal (Markstein).
// R8-verified bit-exact on HW: D=fmax(.,1e-12) normal, num finite; tie
// partners present identical (num,D) bits -> identical q bits.
__device__ __forceinline__ float refine_rcp(float D) {
#pragma clang fp contract(off)
    float r0 = __builtin_amdgcn_rcpf(D);
    float e1 = __builtin_fmaf(-D, r0, 1.0f);
    return __builtin_fmaf(e1, r0, r0);
}
__device__ __forceinline__ float div_rn(float num, float D, float r) {
#pragma clang fp contract(off)
    float q0 = num * r;
    float e  = __builtin_fmaf(-D, q0, num);
    return __builtin_fmaf(e, r, q0);
}

// Scalar region-select, bit-exact vs numpy (proven R2..R12).
__device__ __forceinline__ void region_select(
    float d1, float d2, float d3, float d4, float d5, float d6,
    float va, float vb, float vc, float d43, float d56,
    float g1, float g2, float g3, float g4,
    float& bu, float& bv, float& bw)
{
#pragma clang fp contract(off)
    float G1 = fmaxf(g1, 1e-12f);
    float G2 = fmaxf(g2, 1e-12f);
    float G3 = fmaxf(g3, 1e-12f);
    float G4 = fmaxf(g4, 1e-12f);

    bool cA  = (d1 <= 0.f) & (d2 <= 0.f);
    bool cB  = (d3 >= 0.f) & (d4 <= d3);
    bool cAB = (vc <= 0.f) & (d1 >= 0.f) & (d3 <= 0.f);
    bool cC  = (d6 >= 0.f) & (d5 <= d6);
    bool cAC = (vb <= 0.f) & (d2 >= 0.f) & (d6 <= 0.f);
    bool cBC = (va <= 0.f) & (d43 >= 0.f) & (d56 >= 0.f);

    float nv = cA ? 0.f : cB ? 1.f : cAB ? d1 : cC ? 0.f
             : cAC ? 0.f : cBC ? d43 : vb;
    float nw = cA ? 0.f : cB ? 0.f : cAB ? 0.f : cC ? 1.f
             : cAC ? d2 : cBC ? d43 : vc;
    float D  = cA ? 1.f : cB ? 1.f : cAB ? G1 : cC ? 1.f
             : cAC ? G2 : cBC ? G3 : G4;
    bool fBC = cBC && !(cA || cB || cAB || cC || cAC);

    float r   = refine_rcp(D);
    float qv  = div_rn(nv, D, r);
    float bww = div_rn(nw, D, r);
    float bvv = fBC ? (1.0f - qv) : qv;
    bv = bvv; bw = bww;
    bu = (1.0f - bvv) - bww;
}

// Exact scalar point-vs-tri, R8's verbatim op order (bit-exact vs numpy).
__device__ __forceinline__ float eval_exact(
    float px, float py, float pz,
    float ax, float ay, float az,
    float bx, float by, float bz,
    float cx, float cy, float cz)
{
#pragma clang fp contract(off)
    float abx = bx - ax, aby = by - ay, abz = bz - az;
    float acx = cx - ax, acy = cy - ay, acz = cz - az;
    float apx = px - ax, apy = py - ay, apz = pz - az;
    float d1 = (abx * apx + aby * apy) + abz * apz;
    float d2 = (acx * apx + acy * apy) + acz * apz;
    float bpx = px - bx, bpy = py - by, bpz = pz - bz;
    float d3 = (abx * bpx + aby * bpy) + abz * bpz;
    float d4 = (acx * bpx + acy * bpy) + acz * bpz;
    float cpx = px - cx, cpy = py - cy, cpz = pz - cz;
    float d5 = (abx * cpx + aby * cpy) + abz * cpz;
    float d6 = (acx * cpx + acy * cpy) + acz * cpz;

    float vc = d1 * d4 - d3 * d2;
    float vb = d5 * d2 - d1 * d6;
    float va = d3 * d6 - d5 * d4;
    float d43 = d4 - d3, d56 = d5 - d6;
    float g1 = d1 - d3, g2 = d2 - d6, g3 = d43 + d56, g4 = (va + vb) + vc;

    float bu, bv, bw;
    region_select(d1, d2, d3, d4, d5, d6, va, vb, vc, d43, d56,
                  g1, g2, g3, g4, bu, bv, bw);

    float cpx2 = (ax * bu + bx * bv) + cx * bw;
    float cpy2 = (ay * bu + by * bv) + cy * bw;
    float cpz2 = (az * bu + bz * bv) + cz * bw;
    float dx = px - cpx2, dy = py - cpy2, dz = pz - cpz2;
    return (dx * dx + dy * dy) + dz * dz;
}

// Wave-per-point branch-and-bound scan.
// lb = squared plane distance (valid lower bound on point-tri dist2; n-hat
// precomputed at staging, degenerate normal -> lb=0 never pruned).
// ub = min(vertex-distance bound from chunk 0, exact dist2 seen so far).
// Prune tri iff lb > ub*1.02+1e-18 (margin >> fp error -> argmin and all its
// tie partners always survive; exact eval is R8's bit-exact path, and the
// packed (bits,idx) min over survivors is order-independent -> first-match
// argmin semantics preserved). Survivors ballot-compacted to a per-wave LDS
// list, evaluated lane-parallel (kills exec-mask divergence).
__global__ __launch_bounds__(TPB) void msdf_main(
    const float* __restrict__ verts, const int* __restrict__ faces,
    const float* __restrict__ points, float* __restrict__ out)
{
    __shared__ float sT[13][CHUNK];      // 0-8 verts; 9-11 n-hat; 12 n-hat.a
    __shared__ int   slist[4][CHUNK];    // per-wave survivor list
    const int tid  = threadIdx.x;
    const int lane = tid & 63;
    const int w    = tid >> 6;
    const int p    = blockIdx.x * 4 + w;          // wave-uniform point id

    const float px = points[3 * p], py = points[3 * p + 1], pz = points[3 * p + 2];

    unsigned int best_bits = 0xFFFFFFFFu;
    int best_idx = 0;
    float ub = FLT_MAX;

    for (int c = 0; c < NCHUNK; ++c) {
        __syncthreads();                 // protect LDS buffer reuse
        {   // stage tri c*256+tid: verts + guarded unit normal
            int tg = c * CHUNK + tid;
            int i0 = faces[3 * tg + 0], i1 = faces[3 * tg + 1], i2 = faces[3 * tg + 2];
            float ax = verts[3 * i0], ay = verts[3 * i0 + 1], az = verts[3 * i0 + 2];
            float bx = verts[3 * i1], by = verts[3 * i1 + 1], bz = verts[3 * i1 + 2];
            float cx = verts[3 * i2], cy = verts[3 * i2 + 1], cz = verts[3 * i2 + 2];
            sT[0][tid] = ax; sT[1][tid] = ay; sT[2][tid] = az;
            sT[3][tid] = bx; sT[4][tid] = by; sT[5][tid] = bz;
            sT[6][tid] = cx; sT[7][tid] = cy; sT[8][tid] = cz;
            float e1x = bx - ax, e1y = by - ay, e1z = bz - az;
            float e2x = cx - ax, e2y = cy - ay, e2z = cz - az;
            float nx = e1y * e2z - e1z * e2y;
            float ny = e1z * e2x - e1x * e2z;
            float nz = e1x * e2y - e1y * e2x;
            float nn = (nx * nx + ny * ny) + nz * nz;
            float inv = (nn > 1e-30f) ? (1.0f / sqrtf(nn)) : 0.0f;
            nx *= inv; ny *= inv; nz *= inv;
            sT[9][tid] = nx; sT[10][tid] = ny; sT[11][tid] = nz;
            sT[12][tid] = (nx * ax + ny * ay) + nz * az;
        }
        __syncthreads();

        // chunk 0 only: vertex-distance upper bound seed
        if (c == 0) {
            float u = FLT_MAX;
            #pragma unroll
            for (int s = 0; s < 4; ++s) {
                int t = s * 64 + lane;
                float dx = px - sT[0][t], dy = py - sT[1][t], dz = pz - sT[2][t];
                u = fminf(u, (dx * dx + dy * dy) + dz * dz);
            }
            #pragma unroll
            for (int off = 32; off; off >>= 1)
                u = fminf(u, __shfl_xor(u, off, 64));
            ub = fminf(ub, u);
        }

        // phase 1: plane lower bound + ballot compaction
        int cnt = 0;
        const float ubm = ub * 1.02f + 1e-18f;
        #pragma unroll
        for (int s = 0; s < 4; ++s) {
            int t = s * 64 + lane;
            float lv = ((sT[9][t] * px + sT[10][t] * py) + sT[11][t] * pz) - sT[12][t];
            float lb = lv * lv;
            bool pred = (lb <= ubm);
            unsigned long long m = __ballot(pred);
            if (pred) {
                int off = (int)__popcll(m & ((1ull << lane) - 1ull));
                slist[w][cnt + off] = t;
            }
            cnt += (int)__popcll(m);
        }
        __threadfence_block();           // order slist writes before reads

        // phase 2: exact eval of survivors (lane-parallel over the list)
        float ubc = FLT_MAX;
        for (int j = lane; j < cnt; j += 64) {
            int t = slist[w][j];
            float d2v = eval_exact(px, py, pz,
                sT[0][t], sT[1][t], sT[2][t],
                sT[3][t], sT[4][t], sT[5][t],
                sT[6][t], sT[7][t], sT[8][t]);
            unsigned int bits = __float_as_uint(d2v);
            int gi = c * CHUNK + t;      // per-lane indices ascend -> strict <
            if (bits < best_bits) { best_bits = bits; best_idx = gi; }
            ubc = fminf(ubc, d2v);
        }
        #pragma unroll
        for (int off = 32; off; off >>= 1)
            ubc = fminf(ubc, __shfl_xor(ubc, off, 64));
        ub = fminf(ub, ubc);             // exact-dist ub: razor-sharp pruning
    }

    // in-wave packed min: smallest (bits, idx) == first-match argmin
    unsigned long long key =
        ((unsigned long long)best_bits << 32) | (unsigned int)best_idx;
    #pragma unroll
    for (int off = 32; off > 0; off >>= 1) {
        unsigned int hi = (unsigned int)(key >> 32);
        unsigned int lo = (unsigned int)(key & 0xFFFFFFFFu);
        unsigned int ohi = __shfl_down(hi, off, 64);
        unsigned int olo = __shfl_down(lo, off, 64);
        unsigned long long ok = ((unsigned long long)ohi << 32) | olo;
        key = (ok < key) ? ok : key;
    }
    if (lane == 0) {
        out[1 + p]           = __uint_as_float((unsigned int)(key >> 32));
        out[1 + P_TOTAL + p] = (float)(unsigned int)(key & 0xFFFFFFFFu);
    }
}

// Deterministic single-block loss reduction: out[0] = sum(dist) * 1000/P.
// No atomics (R5: 8192 same-address atomicAdds cost +66us serialized tail).
__global__ __launch_bounds__(256) void msdf_loss(float* __restrict__ out)
{
    __shared__ float wsum[4];
    float s = 0.f;
    for (int k = 0; k < P_TOTAL / 256; ++k)
        s += out[1 + k * 256 + threadIdx.x];
    #pragma unroll
    for (int off = 32; off > 0; off >>= 1) s += __shfl_down(s, off, 64);
    int lane = threadIdx.x & 63, w = threadIdx.x >> 6;
    if (lane == 0) wsum[w] = s;
    __syncthreads();
    if (threadIdx.x == 0) {
        float tot = ((wsum[0] + wsum[1]) + wsum[2]) + wsum[3];
        out[0] = tot * (1000.0f / (float)P_TOTAL);
    }
}

extern "C" void kernel_launch(void* const* d_in, const int* in_sizes, int n_in,
                              void* d_out, int out_size, void* d_ws, size_t ws_size,
                              hipStream_t stream) {
    const float* verts  = (const float*)d_in[0];
    const int*   faces  = (const int*)d_in[1];
    const float* points = (const float*)d_in[2];
    float* out = (float*)d_out;

    msdf_main<<<dim3(P_TOTAL / 4), dim3(TPB), 0, stream>>>(verts, faces, points, out);
    msdf_loss<<<dim3(1), dim3(256), 0, stream>>>(out);
}

// Round 14
// 88.035 us; speedup vs baseline: 1.2541x; 1.0984x over previous
//
#include <hip/hip_runtime.h>
#include <float.h>

#define P_TOTAL 8192
#define F_TOTAL 2048
#define TPB     256                      // 4 independent waves (no barriers)
#define CHUNK   256
#define NCHUNK  (F_TOTAL / CHUNK)        // 8

// Correctly-rounded f32 division via shared refined reciprocal (Markstein).
// R8-verified bit-exact on HW.
__device__ __forceinline__ float refine_rcp(float D) {
#pragma clang fp contract(off)
    float r0 = __builtin_amdgcn_rcpf(D);
    float e1 = __builtin_fmaf(-D, r0, 1.0f);
    return __builtin_fmaf(e1, r0, r0);
}
__device__ __forceinline__ float div_rn(float num, float D, float r) {
#pragma clang fp contract(off)
    float q0 = num * r;
    float e  = __builtin_fmaf(-D, q0, num);
    return __builtin_fmaf(e, r, q0);
}

// Scalar region-select, bit-exact vs numpy (proven R2..R13).
__device__ __forceinline__ void region_select(
    float d1, float d2, float d3, float d4, float d5, float d6,
    float va, float vb, float vc, float d43, float d56,
    float g1, float g2, float g3, float g4,
    float& bu, float& bv, float& bw)
{
#pragma clang fp contract(off)
    float G1 = fmaxf(g1, 1e-12f);
    float G2 = fmaxf(g2, 1e-12f);
    float G3 = fmaxf(g3, 1e-12f);
    float G4 = fmaxf(g4, 1e-12f);

    bool cA  = (d1 <= 0.f) & (d2 <= 0.f);
    bool cB  = (d3 >= 0.f) & (d4 <= d3);
    bool cAB = (vc <= 0.f) & (d1 >= 0.f) & (d3 <= 0.f);
    bool cC  = (d6 >= 0.f) & (d5 <= d6);
    bool cAC = (vb <= 0.f) & (d2 >= 0.f) & (d6 <= 0.f);
    bool cBC = (va <= 0.f) & (d43 >= 0.f) & (d56 >= 0.f);

    float nv = cA ? 0.f : cB ? 1.f : cAB ? d1 : cC ? 0.f
             : cAC ? 0.f : cBC ? d43 : vb;
    float nw = cA ? 0.f : cB ? 0.f : cAB ? 0.f : cC ? 1.f
             : cAC ? d2 : cBC ? d43 : vc;
    float D  = cA ? 1.f : cB ? 1.f : cAB ? G1 : cC ? 1.f
             : cAC ? G2 : cBC ? G3 : G4;
    bool fBC = cBC && !(cA || cB || cAB || cC || cAC);

    float r   = refine_rcp(D);
    float qv  = div_rn(nv, D, r);
    float bww = div_rn(nw, D, r);
    float bvv = fBC ? (1.0f - qv) : qv;
    bv = bvv; bw = bww;
    bu = (1.0f - bvv) - bww;
}

// Exact point-vs-tri, R8's verbatim op order (bit-exact vs numpy).
__device__ __forceinline__ float eval_exact(
    float px, float py, float pz, float4 q0, float4 q1, float4 q2)
{
#pragma clang fp contract(off)
    float ax = q0.x, ay = q0.y, az = q0.z;
    float bx = q0.w, by = q1.x, bz = q1.y;
    float cx = q1.z, cy = q1.w, cz = q2.x;

    float abx = bx - ax, aby = by - ay, abz = bz - az;
    float acx = cx - ax, acy = cy - ay, acz = cz - az;
    float apx = px - ax, apy = py - ay, apz = pz - az;
    float d1 = (abx * apx + aby * apy) + abz * apz;
    float d2 = (acx * apx + acy * apy) + acz * apz;
    float bpx = px - bx, bpy = py - by, bpz = pz - bz;
    float d3 = (abx * bpx + aby * bpy) + abz * bpz;
    float d4 = (acx * bpx + acy * bpy) + acz * bpz;
    float cpx = px - cx, cpy = py - cy, cpz = pz - cz;
    float d5 = (abx * cpx + aby * cpy) + abz * cpz;
    float d6 = (acx * cpx + acy * cpy) + acz * cpz;

    float vc = d1 * d4 - d3 * d2;
    float vb = d5 * d2 - d1 * d6;
    float va = d3 * d6 - d5 * d4;
    float d43 = d4 - d3, d56 = d5 - d6;
    float g1 = d1 - d3, g2 = d2 - d6, g3 = d43 + d56, g4 = (va + vb) + vc;

    float bu, bv, bw;
    region_select(d1, d2, d3, d4, d5, d6, va, vb, vc, d43, d56,
                  g1, g2, g3, g4, bu, bv, bw);

    float cpx2 = (ax * bu + bx * bv) + cx * bw;
    float cpy2 = (ay * bu + by * bv) + cy * bw;
    float cpz2 = (az * bu + bz * bv) + cz * bw;
    float dx = px - cpx2, dy = py - cpy2, dz = pz - cpz2;
    return (dx * dx + dy * dy) + dz * dz;
}

// Prep: once per launch, per-tri plane {n-hat, n-hat.a} + packed verts.
// (Removes R13's 2048x-redundant per-block gather + normal math.)
// |n-hat| <= 1+~2e-7: plane lb then under/over-estimates by ~2e-7 rel,
// covered by the 2% prune margin.
__global__ __launch_bounds__(256) void msdf_prep(
    const float* __restrict__ verts, const int* __restrict__ faces,
    float4* __restrict__ pre_n, float4* __restrict__ pre_v)
{
    int t = blockIdx.x * 256 + threadIdx.x;
    int i0 = faces[3 * t + 0], i1 = faces[3 * t + 1], i2 = faces[3 * t + 2];
    float ax = verts[3 * i0], ay = verts[3 * i0 + 1], az = verts[3 * i0 + 2];
    float bx = verts[3 * i1], by = verts[3 * i1 + 1], bz = verts[3 * i1 + 2];
    float cx = verts[3 * i2], cy = verts[3 * i2 + 1], cz = verts[3 * i2 + 2];
    float e1x = bx - ax, e1y = by - ay, e1z = bz - az;
    float e2x = cx - ax, e2y = cy - ay, e2z = cz - az;
    float nx = e1y * e2z - e1z * e2y;
    float ny = e1z * e2x - e1x * e2z;
    float nz = e1x * e2y - e1y * e2x;
    float nn = (nx * nx + ny * ny) + nz * nz;
    float inv = (nn > 1e-30f) ? (1.0f / sqrtf(nn)) : 0.0f;  // degen -> lb=0
    nx *= inv; ny *= inv; nz *= inv;
    pre_n[t] = make_float4(nx, ny, nz, (nx * ax + ny * ay) + nz * az);
    pre_v[3 * t + 0] = make_float4(ax, ay, az, bx);
    pre_v[3 * t + 1] = make_float4(by, bz, cx, cy);
    pre_v[3 * t + 2] = make_float4(cz, 0.f, 0.f, 0.f);
}

// Wave-per-point branch-and-bound, barrier-free. Phase 1: plane lb vs ub,
// ballot-compacted into a per-wave FIFO ring (LDS). Flush = one FULL 64-lane
// exact-eval body only when >=64 pending (masked drain after chunk 0 to
// sharpen ub, and at the end). Prune margin 2% >> all fp error sources ->
// the argmin and its exact-tie partners always survive; survivors get R8's
// bit-exact eval; packed (bits,idx) min is order-independent -> first-match
// argmin preserved. FIFO ascending -> per-lane strict-< streams ascending.
__global__ __launch_bounds__(TPB) void msdf_main(
    const float4* __restrict__ pre_n, const float4* __restrict__ pre_v,
    const float* __restrict__ points, float* __restrict__ out)
{
    __shared__ int slist[4][512];        // per-wave survivor ring (8 KB)
    const int tid  = threadIdx.x;
    const int lane = tid & 63;
    const int w    = tid >> 6;
    const int p    = blockIdx.x * 4 + w;

    const float px = points[3 * p], py = points[3 * p + 1], pz = points[3 * p + 2];

    // ub seed: A-vertex distances of tris 0..255 (valid: actual mesh points)
    float u = FLT_MAX;
    #pragma unroll
    for (int s = 0; s < 4; ++s) {
        float4 q = pre_v[3 * (s * 64 + lane)];
        float dx = px - q.x, dy = py - q.y, dz = pz - q.z;
        u = fminf(u, (dx * dx + dy * dy) + dz * dz);
    }
    #pragma unroll
    for (int off = 32; off; off >>= 1)
        u = fminf(u, __shfl_xor(u, off, 64));
    float ub = u;

    unsigned int best_bits = 0xFFFFFFFFu;
    int best_idx = 0;
    int pend = 0, h = 0;

    for (int c = 0; c < NCHUNK; ++c) {
        const float ubm = ub * 1.02f + 1e-18f;
        #pragma unroll
        for (int s = 0; s < 4; ++s) {
            int t = c * CHUNK + s * 64 + lane;
            float4 n = pre_n[t];
            float lv = ((n.x * px + n.y * py) + n.z * pz) - n.w;
            bool pred = (lv * lv <= ubm);
            unsigned long long m = __ballot(pred);
            if (pred) {
                int off = (int)__popcll(m & ((1ull << lane) - 1ull));
                slist[w][(h + pend + off) & 511] = t;
            }
            pend += (int)__popcll(m);
        }
        // flush: full 64-lane bodies; drain after chunk 0 and at the end
        bool drain = (c == 0) || (c == NCHUNK - 1);
        while (pend >= 64 || (drain && pend > 0)) {
            int n_ev = pend < 64 ? pend : 64;
            int j = (lane < n_ev) ? lane : 0;       // dup of head: idempotent
            int t = slist[w][(h + j) & 511];
            float4 q0 = pre_v[3 * t + 0];
            float4 q1 = pre_v[3 * t + 1];
            float4 q2 = pre_v[3 * t + 2];
            float d2v = eval_exact(px, py, pz, q0, q1, q2);
            unsigned int bits = __float_as_uint(d2v);
            if (bits < best_bits) { best_bits = bits; best_idx = t; }
            float ubc = d2v;
            #pragma unroll
            for (int off = 32; off; off >>= 1)
                ubc = fminf(ubc, __shfl_xor(ubc, off, 64));
            ub = fminf(ub, ubc);
            h += n_ev; pend -= n_ev;
        }
    }

    // in-wave packed min: smallest (bits, idx) == first-match argmin
    unsigned long long key =
        ((unsigned long long)best_bits << 32) | (unsigned int)best_idx;
    #pragma unroll
    for (int off = 32; off > 0; off >>= 1) {
        unsigned int hi = (unsigned int)(key >> 32);
        unsigned int lo = (unsigned int)(key & 0xFFFFFFFFu);
        unsigned int ohi = __shfl_down(hi, off, 64);
        unsigned int olo = __shfl_down(lo, off, 64);
        unsigned long long ok = ((unsigned long long)ohi << 32) | olo;
        key = (ok < key) ? ok : key;
    }
    if (lane == 0) {
        out[1 + p]           = __uint_as_float((unsigned int)(key >> 32));
        out[1 + P_TOTAL + p] = (float)(unsigned int)(key & 0xFFFFFFFFu);
    }
}

// Deterministic single-block loss reduction: out[0] = sum(dist) * 1000/P.
// No atomics (R5: 8192 same-address atomicAdds cost +66us serialized tail).
__global__ __launch_bounds__(256) void msdf_loss(float* __restrict__ out)
{
    __shared__ float wsum[4];
    float s = 0.f;
    for (int k = 0; k < P_TOTAL / 256; ++k)
        s += out[1 + k * 256 + threadIdx.x];
    #pragma unroll
    for (int off = 32; off > 0; off >>= 1) s += __shfl_down(s, off, 64);
    int lane = threadIdx.x & 63, w = threadIdx.x >> 6;
    if (lane == 0) wsum[w] = s;
    __syncthreads();
    if (threadIdx.x == 0) {
        float tot = ((wsum[0] + wsum[1]) + wsum[2]) + wsum[3];
        out[0] = tot * (1000.0f / (float)P_TOTAL);
    }
}

extern "C" void kernel_launch(void* const* d_in, const int* in_sizes, int n_in,
                              void* d_out, int out_size, void* d_ws, size_t ws_size,
                              hipStream_t stream) {
    const float* verts  = (const float*)d_in[0];
    const int*   faces  = (const int*)d_in[1];
    const float* points = (const float*)d_in[2];
    float* out = (float*)d_out;
    float4* pre_n = (float4*)d_ws;                                   // 32 KB
    float4* pre_v = (float4*)((char*)d_ws + F_TOTAL * sizeof(float4)); // 96 KB

    msdf_prep<<<dim3(F_TOTAL / 256), dim3(256), 0, stream>>>(verts, faces, pre_n, pre_v);
    msdf_main<<<dim3(P_TOTAL / 4), dim3(TPB), 0, stream>>>(pre_n, pre_v, points, out);
    msdf_loss<<<dim3(1), dim3(256), 0, stream>>>(out);
}